// Round 6
// baseline (159.229 us; speedup 1.0000x reference)
//
#include <hip/hip_runtime.h>

#define C 128        // IN_CH == OUT_CH
#define NPB 16       // nodes per node-pre block
#define NSLAB 8      // XCD-private bucket slabs (blockIdx & 7 ~ XCD under round-robin)
#define CAP8 24      // per-slab bucket capacity (per-slab mean deg ~8.2, sd ~2.9)
#define OVF_MAX 65536
#define EPT 8        // edges per thread in scatter

__device__ __forceinline__ unsigned bf16_bits(float x) {   // round-to-nearest-even
    unsigned u = __float_as_uint(x);
    u += 0x7FFFu + ((u >> 16) & 1u);
    return u >> 16;
}
__device__ __forceinline__ float bf16f(unsigned short b) {
    return __uint_as_float(((unsigned)b) << 16);
}

// Heterogeneous kernel: blocks [0, SB) scatter edges into XCD-private padded-CSR
// slabs (slab = blockIdx&7, so all writers of a slab line sit on one XCD -> no
// cross-XCD dirty-line bouncing). Blocks [SB, SB+PB) compute P = x@W1[:C] (bf16)
// and Q = x@W1[C:] (fp32); co-scheduling hides the GEMM in the scatter stalls.
__global__ void fused_pre_kernel(const float* __restrict__ x, const float* __restrict__ W1,
                                 unsigned short* __restrict__ P16, float* __restrict__ Q,
                                 const int* __restrict__ ei, const float* __restrict__ attr,
                                 int* __restrict__ cursor, int* __restrict__ ovf_cnt,
                                 int2* __restrict__ ovf, unsigned* __restrict__ sorted,
                                 int N, int E, int SB) {
    if ((int)blockIdx.x < SB) {
        const int slab = blockIdx.x & (NSLAB - 1);
        int* __restrict__ cur = cursor + (size_t)slab * N;
        unsigned* __restrict__ sl = sorted + (size_t)slab * N * CAP8;
        const int base = (blockIdx.x * 256 + threadIdx.x) * EPT;
        if (base >= E) return;
        if (base + EPT <= E) {
            const int4 r0 = *(const int4*)(ei + base);
            const int4 r1 = *(const int4*)(ei + base + 4);
            const int4 c0 = *(const int4*)(ei + (size_t)E + base);
            const int4 c1 = *(const int4*)(ei + (size_t)E + base + 4);
            const float4 a0 = *(const float4*)(attr + base);
            const float4 a1 = *(const float4*)(attr + base + 4);
            const int rows[EPT] = {r0.x, r0.y, r0.z, r0.w, r1.x, r1.y, r1.z, r1.w};
            const int cols[EPT] = {c0.x, c0.y, c0.z, c0.w, c1.x, c1.y, c1.z, c1.w};
            const float as[EPT] = {a0.x, a0.y, a0.z, a0.w, a1.x, a1.y, a1.z, a1.w};
            int pos[EPT];
#pragma unroll
            for (int j = 0; j < EPT; ++j)
                pos[j] = atomicAdd(&cur[cols[j]], 1);
#pragma unroll
            for (int j = 0; j < EPT; ++j) {
                const unsigned v = (bf16_bits(as[j]) << 16) | (unsigned)rows[j];
                if (pos[j] < CAP8) {
                    sl[(size_t)cols[j] * CAP8 + pos[j]] = v;
                } else {
                    const int o = atomicAdd(ovf_cnt, 1);
                    if (o < OVF_MAX) ovf[o] = make_int2(cols[j], (int)v);
                }
            }
        } else {
            for (int e = base; e < E; ++e) {
                const int row = ei[e], colv = ei[(size_t)E + e];
                const int pos = atomicAdd(&cur[colv], 1);
                const unsigned v = (bf16_bits(attr[e]) << 16) | (unsigned)row;
                if (pos < CAP8) sl[(size_t)colv * CAP8 + pos] = v;
                else {
                    const int o = atomicAdd(ovf_cnt, 1);
                    if (o < OVF_MAX) ovf[o] = make_int2(colv, (int)v);
                }
            }
        }
    } else {
        // node pre-GEMM: 16 nodes/block, 256 threads (half -> P bf16, half -> Q fp32)
        __shared__ float xs[NPB][C];
        const int pb = blockIdx.x - SB;
        const int n0 = pb * NPB;
        const int tt = threadIdx.x & (C - 1);
        const int half = threadIdx.x >> 7;
        for (int i = threadIdx.x; i < NPB * C; i += 256) {
            const int gi = n0 * C + i;
            xs[0][i] = (gi < N * C) ? x[gi] : 0.f;
        }
        __syncthreads();
        const float* __restrict__ Wb = W1 + (half ? (C * C) : 0) + tt;
        float acc[NPB] = {};
        for (int k = 0; k < C; ++k) {
            const float w = Wb[k * C];
#pragma unroll
            for (int j = 0; j < NPB; ++j)
                acc[j] = fmaf(xs[j][k], w, acc[j]);
        }
#pragma unroll
        for (int j = 0; j < NPB; ++j)
            if (n0 + j < N) {
                if (half) Q[(size_t)(n0 + j) * C + tt] = acc[j];
                else      P16[(size_t)(n0 + j) * C + tt] = (unsigned short)bf16_bits(acc[j]);
            }
    }
}

// Fused aggregation + output GEMM. 2 nodes per 256-thread block.
// Thread (j = t>>7, slice = (t>>5)&3, ch4 = t&31): slice handles slabs {slice, slice+4},
// lane owns 4 channels via ushort4 bf16 gathers of P. LDS-reduce slices -> H,
// then k-sliced W2 matmul with float4 loads, LDS-reduce -> out.
__global__ void agg_out_kernel(const unsigned* __restrict__ sorted, const int* __restrict__ cursor,
                               const unsigned short* __restrict__ P16, const float* __restrict__ Q,
                               const float* __restrict__ b1, const float* __restrict__ W2,
                               const float* __restrict__ b2,
                               const int* __restrict__ ovf_cnt, const int2* __restrict__ ovf,
                               float* __restrict__ out, int N) {
    __shared__ float4 part[2][4][32];
    __shared__ float hs[2][C];
    const int t = threadIdx.x;
    const int j = t >> 7;
    const int slice = (t >> 5) & 3;
    const int ch4 = t & 31;
    const int n = blockIdx.x * 2 + j;

    float4 acc = make_float4(0.f, 0.f, 0.f, 0.f);
    float4 qb = acc;
    int deg = 0;
    if (n < N) {
        int cnts[NSLAB];
#pragma unroll
        for (int s = 0; s < NSLAB; ++s) {
            cnts[s] = cursor[(size_t)s * N + n];
            deg += cnts[s];
        }
        const float4 q4  = *(const float4*)(Q + (size_t)n * C + (ch4 << 2));
        const float4 b14 = *(const float4*)(b1 + (ch4 << 2));
        qb = make_float4(q4.x + b14.x, q4.y + b14.y, q4.z + b14.z, q4.w + b14.w);
#pragma unroll
        for (int si = 0; si < 2; ++si) {
            const int s = slice + (si << 2);
            const int cs = min(cnts[s], CAP8);
            const unsigned* __restrict__ buf = sorted + ((size_t)s * N + n) * CAP8;
            int i = 0;
            for (; i + 4 <= cs; i += 4) {
                const uint4 v = *(const uint4*)(buf + i);
                const ushort4 p0 = *(const ushort4*)(P16 + (((size_t)(v.x & 0xFFFFu)) << 7) + (ch4 << 2));
                const ushort4 p1 = *(const ushort4*)(P16 + (((size_t)(v.y & 0xFFFFu)) << 7) + (ch4 << 2));
                const ushort4 p2 = *(const ushort4*)(P16 + (((size_t)(v.z & 0xFFFFu)) << 7) + (ch4 << 2));
                const ushort4 p3 = *(const ushort4*)(P16 + (((size_t)(v.w & 0xFFFFu)) << 7) + (ch4 << 2));
                const float a0 = __uint_as_float(v.x & 0xFFFF0000u);
                const float a1 = __uint_as_float(v.y & 0xFFFF0000u);
                const float a2 = __uint_as_float(v.z & 0xFFFF0000u);
                const float a3 = __uint_as_float(v.w & 0xFFFF0000u);
                acc.x += fmaxf(fmaf(a0, bf16f(p0.x), qb.x), 0.f) + fmaxf(fmaf(a1, bf16f(p1.x), qb.x), 0.f)
                       + fmaxf(fmaf(a2, bf16f(p2.x), qb.x), 0.f) + fmaxf(fmaf(a3, bf16f(p3.x), qb.x), 0.f);
                acc.y += fmaxf(fmaf(a0, bf16f(p0.y), qb.y), 0.f) + fmaxf(fmaf(a1, bf16f(p1.y), qb.y), 0.f)
                       + fmaxf(fmaf(a2, bf16f(p2.y), qb.y), 0.f) + fmaxf(fmaf(a3, bf16f(p3.y), qb.y), 0.f);
                acc.z += fmaxf(fmaf(a0, bf16f(p0.z), qb.z), 0.f) + fmaxf(fmaf(a1, bf16f(p1.z), qb.z), 0.f)
                       + fmaxf(fmaf(a2, bf16f(p2.z), qb.z), 0.f) + fmaxf(fmaf(a3, bf16f(p3.z), qb.z), 0.f);
                acc.w += fmaxf(fmaf(a0, bf16f(p0.w), qb.w), 0.f) + fmaxf(fmaf(a1, bf16f(p1.w), qb.w), 0.f)
                       + fmaxf(fmaf(a2, bf16f(p2.w), qb.w), 0.f) + fmaxf(fmaf(a3, bf16f(p3.w), qb.w), 0.f);
            }
            for (; i < cs; ++i) {
                const unsigned v = buf[i];
                const ushort4 p = *(const ushort4*)(P16 + (((size_t)(v & 0xFFFFu)) << 7) + (ch4 << 2));
                const float a = __uint_as_float(v & 0xFFFF0000u);
                acc.x += fmaxf(fmaf(a, bf16f(p.x), qb.x), 0.f);
                acc.y += fmaxf(fmaf(a, bf16f(p.y), qb.y), 0.f);
                acc.z += fmaxf(fmaf(a, bf16f(p.z), qb.z), 0.f);
                acc.w += fmaxf(fmaf(a, bf16f(p.w), qb.w), 0.f);
            }
        }
        if (slice == 0) {   // overflow entries (rare)
            const int oc = min(*ovf_cnt, OVF_MAX);
            for (int o = 0; o < oc; ++o) {
                const int2 v = ovf[o];
                if (v.x == n) {
                    const unsigned u = (unsigned)v.y;
                    const ushort4 p = *(const ushort4*)(P16 + (((size_t)(u & 0xFFFFu)) << 7) + (ch4 << 2));
                    const float a = __uint_as_float(u & 0xFFFF0000u);
                    acc.x += fmaxf(fmaf(a, bf16f(p.x), qb.x), 0.f);
                    acc.y += fmaxf(fmaf(a, bf16f(p.y), qb.y), 0.f);
                    acc.z += fmaxf(fmaf(a, bf16f(p.z), qb.z), 0.f);
                    acc.w += fmaxf(fmaf(a, bf16f(p.w), qb.w), 0.f);
                }
            }
        }
    }
    part[j][slice][ch4] = acc;
    __syncthreads();
    if (slice == 0 && n < N) {
        const float4 r0 = part[j][0][ch4], r1 = part[j][1][ch4];
        const float4 r2 = part[j][2][ch4], r3 = part[j][3][ch4];
        float4 h;
        h.x = r0.x + r1.x + r2.x + r3.x;
        h.y = r0.y + r1.y + r2.y + r3.y;
        h.z = r0.z + r1.z + r2.z + r3.z;
        h.w = r0.w + r1.w + r2.w + r3.w;
        *(float4*)(&hs[j][ch4 << 2]) = h;
    }
    __syncthreads();
    // k-sliced matmul: slice covers k in [slice*32, slice*32+32)
    float4 o = make_float4(0.f, 0.f, 0.f, 0.f);
    if (n < N) {
        const int k0 = slice << 5;
#pragma unroll 8
        for (int k = k0; k < k0 + 32; ++k) {
            const float hv = hs[j][k];
            const float4 w = *(const float4*)(W2 + (size_t)k * C + (ch4 << 2));
            o.x = fmaf(hv, w.x, o.x);
            o.y = fmaf(hv, w.y, o.y);
            o.z = fmaf(hv, w.z, o.z);
            o.w = fmaf(hv, w.w, o.w);
        }
    }
    __syncthreads();            // before reusing `part`
    part[j][slice][ch4] = o;
    __syncthreads();
    if (slice == 0 && n < N) {
        const float4 r0 = part[j][0][ch4], r1 = part[j][1][ch4];
        const float4 r2 = part[j][2][ch4], r3 = part[j][3][ch4];
        const float4 b24 = *(const float4*)(b2 + (ch4 << 2));
        const float d = (float)deg;
        float4 res;
        res.x = fmaf(d, b24.x, r0.x + r1.x + r2.x + r3.x);
        res.y = fmaf(d, b24.y, r0.y + r1.y + r2.y + r3.y);
        res.z = fmaf(d, b24.z, r0.z + r1.z + r2.z + r3.z);
        res.w = fmaf(d, b24.w, r0.w + r1.w + r2.w + r3.w);
        *(float4*)(out + (size_t)n * C + (ch4 << 2)) = res;
    }
}

extern "C" void kernel_launch(void* const* d_in, const int* in_sizes, int n_in,
                              void* d_out, int out_size, void* d_ws, size_t ws_size,
                              hipStream_t stream) {
    const float* x    = (const float*)d_in[0];
    const int*   ei   = (const int*)d_in[1];
    const float* attr = (const float*)d_in[2];
    const float* W1   = (const float*)d_in[3];
    const float* b1   = (const float*)d_in[4];
    const float* W2   = (const float*)d_in[5];
    const float* b2   = (const float*)d_in[6];
    float* out = (float*)d_out;

    const int N = in_sizes[0] / C;
    const int E = in_sizes[2];

    char* ws = (char*)d_ws;
    unsigned short* P16 = (unsigned short*)ws;  ws += (size_t)N * C * sizeof(unsigned short);
    ws = (char*)(((uintptr_t)ws + 15) & ~(uintptr_t)15);
    float*    Q       = (float*)ws;     ws += (size_t)N * C * sizeof(float);
    unsigned* sorted  = (unsigned*)ws;  ws += (size_t)NSLAB * N * CAP8 * sizeof(unsigned);
    int2*     ovf     = (int2*)ws;      ws += (size_t)OVF_MAX * sizeof(int2);
    int*      cursor  = (int*)ws;       ws += (size_t)NSLAB * N * sizeof(int);
    int*      ovf_cnt = (int*)ws;

    // zero per-slab cursors + ovf_cnt (contiguous)
    hipMemsetAsync(cursor, 0, ((size_t)NSLAB * N + 1) * sizeof(int), stream);

    const int SB = (E + 256 * EPT - 1) / (256 * EPT);
    const int PB = (N + NPB - 1) / NPB;
    fused_pre_kernel<<<SB + PB, 256, 0, stream>>>(x, W1, P16, Q, ei, attr,
                                                  cursor, ovf_cnt, ovf, sorted, N, E, SB);
    agg_out_kernel<<<(N + 1) / 2, 256, 0, stream>>>(sorted, cursor, P16, Q, b1, W2, b2,
                                                    ovf_cnt, ovf, out, N);
}